// Round 1
// baseline (1046.847 us; speedup 1.0000x reference)
//
#include <hip/hip_runtime.h>
#include <math.h>

#define B_ 8
#define N_ 1024
#define D_ 512
#define H_ 8
#define HD_ 64
#define DS_ 63
#define SCALE_ 0.125f
#define EPS_ 1e-7f

// ---------------- Kernel 1: QKV projections + lorentz time + logmap (V) ----
// grid: (128 row-tiles, H, 3 mats), block 256 (16x16 threads, 4x4 microtile)
// Output layout: [B][H][N][64] fp32.
//   mat0 (Q): [0] = -t*SCALE, [e] = z[e-1]*SCALE   (score = plain dot64)
//   mat1 (K): [0] =  t,       [e] = z[e-1]
//   mat2 (V): [0] =  0,       [e] = coef_log * z[e-1]   (logmap0 tangent)
__global__ void proj_kernel(const float* __restrict__ x,
                            const float* __restrict__ Wq, const float* __restrict__ bq,
                            const float* __restrict__ Wk, const float* __restrict__ bk,
                            const float* __restrict__ Wv, const float* __restrict__ bv,
                            float* __restrict__ Qo, float* __restrict__ Ko,
                            float* __restrict__ Vo)
{
    __shared__ float smem[64*65];          // union: Xs[64][33]+Ws[32][64] | zs[64][65]
    __shared__ float tvals[64], cvals[64];
    float* Xs = smem;                      // stride 33 (bank-conflict-free)
    float* Ws = smem + 64*33;              // [32][64]
    float* zs = smem;                      // [64][65] reused after K-loop

    const int tid = threadIdx.x;
    const int tx = tid & 15, ty = tid >> 4;
    const int h = blockIdx.y, mat = blockIdx.z;
    const int rowBase = blockIdx.x * 64;

    const float* W    = (mat == 0) ? Wq : (mat == 1) ? Wk : Wv;
    const float* bias = (mat == 0) ? bq : (mat == 1) ? bk : bv;
    const float* Wh = W + (size_t)h * D_ * DS_;
    const float* bh = bias + h * DS_;

    float c[4][4];
#pragma unroll
    for (int i = 0; i < 4; i++)
#pragma unroll
        for (int j = 0; j < 4; j++) c[i][j] = 0.f;

    for (int kb = 0; kb < D_; kb += 32) {
        for (int i = tid; i < 64*32; i += 256) {
            int r = i >> 5, cc = i & 31;
            Xs[r*33 + cc] = x[(size_t)(rowBase + r)*D_ + kb + cc];
        }
        for (int i = tid; i < 32*64; i += 256) {
            int k = i >> 6, e = i & 63;
            Ws[i] = (e < DS_) ? Wh[(size_t)(kb + k)*DS_ + e] : 0.f;
        }
        __syncthreads();
#pragma unroll
        for (int k = 0; k < 32; k++) {
            float a[4], bb[4];
#pragma unroll
            for (int i = 0; i < 4; i++) a[i] = Xs[(ty*4 + i)*33 + k];
#pragma unroll
            for (int j = 0; j < 4; j++) bb[j] = Ws[k*64 + tx*4 + j];
#pragma unroll
            for (int i = 0; i < 4; i++)
#pragma unroll
                for (int j = 0; j < 4; j++)
                    c[i][j] = fmaf(a[i], bb[j], c[i][j]);
        }
        __syncthreads();
    }

    // write microtiles (+bias) into zs[64][65]
#pragma unroll
    for (int i = 0; i < 4; i++) {
#pragma unroll
        for (int j = 0; j < 4; j++) {
            int e = tx*4 + j;
            float bv_ = (e < DS_) ? bh[e] : 0.f;
            zs[(ty*4 + i)*65 + e] = c[i][j] + bv_;
        }
    }
    __syncthreads();

    if (tid < 64) {
        float ss = 0.f;
        for (int e = 0; e < DS_; e++) { float v = zs[tid*65 + e]; ss += v*v; }
        float t = sqrtf(ss + 1.f);
        float w0, coef;
        if (mat == 0)      { w0 = -t * SCALE_; coef = SCALE_; }
        else if (mat == 1) { w0 =  t;          coef = 1.f; }
        else {
            float tc = fmaxf(t, 1.f + EPS_);
            float d  = acoshf(tc);
            float dn = sqrtf(fmaxf(t*t - 1.f, EPS_));
            w0 = 0.f; coef = d / dn;
        }
        tvals[tid] = w0; cvals[tid] = coef;
    }
    __syncthreads();

    float* dst = (mat == 0) ? Qo : (mat == 1) ? Ko : Vo;
    for (int i = tid; i < 64*64; i += 256) {
        int r = i >> 6, e = i & 63;
        int g = rowBase + r;
        int b = g >> 10, n = g & (N_ - 1);
        float val = (e == 0) ? tvals[r] : cvals[r] * zs[r*65 + e - 1];
        dst[(((size_t)(b*H_ + h))*N_ + n)*64 + e] = val;
    }
}

// ---------------- Kernel 2: fused attention + expmap0 ----------------------
// grid: (N/128, H, B), block 256 = 4 waves. Wave handles 32 q-rows:
//   lane = (half<<5)|row ; half 0 -> dims 0..31, half 1 -> dims 32..63.
// Scores <= -1/8  =>  exp never overflows; single-pass exp-sum (no flash max).
__global__ void attn_kernel(const float* __restrict__ Q, const float* __restrict__ K,
                            const float* __restrict__ V, float* __restrict__ out,
                            float* __restrict__ TS, float sconst)
{
    __shared__ float Klds[64*64];
    __shared__ float Vlds[64*64];
    const int tid  = threadIdx.x;
    const int wid  = tid >> 6;
    const int lane = tid & 63;
    const int rl = lane & 31, half = lane >> 5;
    const int bh  = blockIdx.z * H_ + blockIdx.y;
    const int row = blockIdx.x * 128 + wid*32 + rl;

    const size_t qbase = (((size_t)bh)*N_ + row)*64 + half*32;
    float q[32], acc[32];
#pragma unroll
    for (int e = 0; e < 32; e++) { q[e] = Q[qbase + e]; acc[e] = 0.f; }
    float den = 0.f;

    const size_t kvbase = ((size_t)bh)*N_*64;
    for (int kt = 0; kt < N_; kt += 64) {
        __syncthreads();
        for (int i = tid; i < 64*64; i += 256) {
            Klds[i] = K[kvbase + (size_t)kt*64 + i];
            Vlds[i] = V[kvbase + (size_t)kt*64 + i];
        }
        __syncthreads();
#pragma unroll 2
        for (int j = 0; j < 64; j++) {
            const float* kr = &Klds[j*64 + half*32];
            float s0 = 0.f, s1 = 0.f, s2 = 0.f, s3 = 0.f;
#pragma unroll
            for (int e = 0; e < 8; e++) {
                s0 = fmaf(q[e],      kr[e],      s0);
                s1 = fmaf(q[e + 8],  kr[e + 8],  s1);
                s2 = fmaf(q[e + 16], kr[e + 16], s2);
                s3 = fmaf(q[e + 24], kr[e + 24], s3);
            }
            float sp = (s0 + s1) + (s2 + s3);
            float s  = sp + __shfl_xor(sp, 32);
            float p  = __expf(s);          // s <= -0.125, safe
            den += p;
            const float* vr = &Vlds[j*64 + half*32];
#pragma unroll
            for (int e = 0; e < 32; e++) acc[e] = fmaf(p, vr[e], acc[e]);
        }
    }

    float inv = 1.f / den;
    float ss = 0.f;
#pragma unroll
    for (int e = 0; e < 32; e++) { acc[e] *= inv; ss += acc[e]*acc[e]; }
    float rsq = ss + __shfl_xor(ss, 32);
    float r   = sqrtf(fmaxf(rsq, 1e-14f));   // EPS^2
    float t   = coshf(r);
    float coef = sconst * sinhf(r) / r;

    const int b = bh >> 3, h = bh & 7;
    const size_t obase = ((size_t)b*N_ + row)*505;
#pragma unroll
    for (int e = 0; e < 32; e++) {
        int ge = half*32 + e;
        if (ge >= 1) out[obase + 1 + h*DS_ + ge - 1] = coef * acc[e];
    }
    if (half == 0) TS[((size_t)bh)*N_ + row] = t;
}

// ---------------- Kernel 3: cross-head t' --------------------------------
__global__ void tprime_kernel(const float* __restrict__ TS, float* __restrict__ out,
                              float sconst)
{
    int idx = blockIdx.x*256 + threadIdx.x;   // b*N + n
    if (idx >= B_*N_) return;
    int b = idx >> 10, n = idx & (N_ - 1);
    float sum = 0.f;
#pragma unroll
    for (int h = 0; h < H_; h++) {
        float t = TS[((size_t)(b*H_ + h))*N_ + n];
        sum += t*t - 1.f;    // invK = -1
    }
    float tp = sqrtf(fmaxf(sconst*sconst*sum + 1.f, 1e-8f));
    out[(size_t)idx*505] = tp;
}

static double digamma_(double x) {
    double r = 0.0;
    while (x < 20.0) { r -= 1.0/x; x += 1.0; }
    double f = 1.0/(x*x);
    return r + log(x) - 0.5/x - f*(1.0/12.0 - f*(1.0/120.0 - f*(1.0/252.0)));
}

extern "C" void kernel_launch(void* const* d_in, const int* in_sizes, int n_in,
                              void* d_out, int out_size, void* d_ws, size_t ws_size,
                              hipStream_t stream) {
    const float* x  = (const float*)d_in[0];
    const float* Wq = (const float*)d_in[1];
    const float* bq = (const float*)d_in[2];
    const float* Wk = (const float*)d_in[3];
    const float* bk = (const float*)d_in[4];
    const float* Wv = (const float*)d_in[5];
    const float* bv = (const float*)d_in[6];
    float* out = (float*)d_out;

    // workspace: Q | K | Vtan  [B][H][N][64]  + TS [B][H][N]   (~48.3 MB)
    float* ws = (float*)d_ws;
    const size_t QKV = (size_t)B_*H_*N_*64;
    float* Qd = ws;
    float* Kd = ws + QKV;
    float* Vd = ws + 2*QKV;
    float* TS = ws + 3*QKV;

    const float sconst = (float)exp(0.5*(digamma_(H_*DS_/2.0) - digamma_(DS_/2.0)));

    dim3 g1(128, H_, 3);
    proj_kernel<<<g1, 256, 0, stream>>>(x, Wq, bq, Wk, bk, Wv, bv, Qd, Kd, Vd);
    dim3 g2(N_/128, H_, B_);
    attn_kernel<<<g2, 256, 0, stream>>>(Qd, Kd, Vd, out, TS, sconst);
    tprime_kernel<<<(B_*N_ + 255)/256, 256, 0, stream>>>(TS, out, sconst);
}

// Round 2
// 303.737 us; speedup vs baseline: 3.4466x; 3.4466x over previous
//
#include <hip/hip_runtime.h>
#include <math.h>

#define B_ 8
#define N_ 1024
#define D_ 512
#define H_ 8
#define HD_ 64
#define DS_ 63
#define SCALE_ 0.125f
#define EPS_ 1e-7f
#define KT_ 64

typedef short bf16x8 __attribute__((ext_vector_type(8)));   // 8 bf16 in 4 VGPRs
typedef float f32x16 __attribute__((ext_vector_type(16)));

__device__ inline ushort f2bf(float f) {
    uint u = __float_as_uint(f);
    uint r = (u + 0x7FFFu + ((u >> 16) & 1u)) >> 16;
    return (ushort)r;
}

// ---------------- Kernel 1: QKV projections (fp32 compute, bf16 out) -------
// grid: (128 row-tiles, H, 3 mats), block 256 (16x16 threads, 4x4 microtile)
//   mat0 (Q): [B][H][N][64] bf16, [0]=-t*SCALE, [e]=z[e-1]*SCALE
//   mat1 (K): [B][H][N][64] bf16, [0]= t,       [e]=z[e-1]
//   mat2 (Vt): TRANSPOSED [B][H][64][N] bf16, row0 = 0, row e = coef_log*z[e-1]
__global__ void proj_kernel(const float* __restrict__ x,
                            const float* __restrict__ Wq, const float* __restrict__ bq,
                            const float* __restrict__ Wk, const float* __restrict__ bk,
                            const float* __restrict__ Wv, const float* __restrict__ bv,
                            ushort* __restrict__ Qo, ushort* __restrict__ Ko,
                            ushort* __restrict__ Vto)
{
    __shared__ float smem[64*65];          // union: Xs[64][33]+Ws[32][64] | zs[64][65]
    __shared__ float tvals[64], cvals[64];
    float* Xs = smem;
    float* Ws = smem + 64*33;
    float* zs = smem;

    const int tid = threadIdx.x;
    const int tx = tid & 15, ty = tid >> 4;
    const int h = blockIdx.y, mat = blockIdx.z;
    const int rowBase = blockIdx.x * 64;

    const float* W    = (mat == 0) ? Wq : (mat == 1) ? Wk : Wv;
    const float* bias = (mat == 0) ? bq : (mat == 1) ? bk : bv;
    const float* Wh = W + (size_t)h * D_ * DS_;
    const float* bh = bias + h * DS_;

    float c[4][4];
#pragma unroll
    for (int i = 0; i < 4; i++)
#pragma unroll
        for (int j = 0; j < 4; j++) c[i][j] = 0.f;

    for (int kb = 0; kb < D_; kb += 32) {
        for (int i = tid; i < 64*32; i += 256) {
            int r = i >> 5, cc = i & 31;
            Xs[r*33 + cc] = x[(size_t)(rowBase + r)*D_ + kb + cc];
        }
        for (int i = tid; i < 32*64; i += 256) {
            int k = i >> 6, e = i & 63;
            Ws[i] = (e < DS_) ? Wh[(size_t)(kb + k)*DS_ + e] : 0.f;
        }
        __syncthreads();
#pragma unroll
        for (int k = 0; k < 32; k++) {
            float a[4], bb[4];
#pragma unroll
            for (int i = 0; i < 4; i++) a[i] = Xs[(ty*4 + i)*33 + k];
#pragma unroll
            for (int j = 0; j < 4; j++) bb[j] = Ws[k*64 + tx*4 + j];
#pragma unroll
            for (int i = 0; i < 4; i++)
#pragma unroll
                for (int j = 0; j < 4; j++)
                    c[i][j] = fmaf(a[i], bb[j], c[i][j]);
        }
        __syncthreads();
    }

#pragma unroll
    for (int i = 0; i < 4; i++) {
#pragma unroll
        for (int j = 0; j < 4; j++) {
            int e = tx*4 + j;
            float bv_ = (e < DS_) ? bh[e] : 0.f;
            zs[(ty*4 + i)*65 + e] = c[i][j] + bv_;
        }
    }
    __syncthreads();

    if (tid < 64) {
        float ss = 0.f;
        for (int e = 0; e < DS_; e++) { float v = zs[tid*65 + e]; ss += v*v; }
        float t = sqrtf(ss + 1.f);
        float w0, coef;
        if (mat == 0)      { w0 = -t * SCALE_; coef = SCALE_; }
        else if (mat == 1) { w0 =  t;          coef = 1.f; }
        else {
            float tc = fmaxf(t, 1.f + EPS_);
            float d  = acoshf(tc);
            float dn = sqrtf(fmaxf(t*t - 1.f, EPS_));
            w0 = 0.f; coef = d / dn;
        }
        tvals[tid] = w0; cvals[tid] = coef;
    }
    __syncthreads();

    if (mat == 2) {
        // transposed write: consecutive tid -> consecutive n (coalesced)
        for (int i = tid; i < 64*64; i += 256) {
            int e = i >> 6, rr = i & 63;
            int g = rowBase + rr;
            int b = g >> 10, n = g & (N_ - 1);
            float val = (e == 0) ? 0.f : cvals[rr] * zs[rr*65 + e - 1];
            Vto[(((size_t)(b*H_ + h))*64 + e)*N_ + n] = f2bf(val);
        }
    } else {
        ushort* dst = (mat == 0) ? Qo : Ko;
        for (int i = tid; i < 64*64; i += 256) {
            int rr = i >> 6, e = i & 63;
            int g = rowBase + rr;
            int b = g >> 10, n = g & (N_ - 1);
            float val = (e == 0) ? tvals[rr] : cvals[rr] * zs[rr*65 + e - 1];
            dst[(((size_t)(b*H_ + h))*N_ + n)*64 + e] = f2bf(val);
        }
    }
}

// ---------------- Kernel 2: MFMA attention + expmap0 -----------------------
// grid: (N/128, H, B), block 256 = 4 waves; wave owns 32 q-rows.
// S^T = mfma(K, Q)  (shared k-permutation => layout-safe)
// out^T = mfma(V^T, P^T)  (P^T C/D regs [8c..8c+8) ARE the B-frag for n-half c)
__global__ __launch_bounds__(256, 2)
void attn_kernel(const ushort* __restrict__ Q, const ushort* __restrict__ K,
                 const ushort* __restrict__ Vt, float* __restrict__ out,
                 float* __restrict__ TS, float sconst)
{
    __shared__ ushort Klds[KT_*64];   // [key n][e], rows 128B, XOR (n&7)<<4
    __shared__ ushort Vlds[64*KT_];   // [d][n],    rows 128B, XOR (d&7)<<3

    const int tid  = threadIdx.x;
    const int wid  = tid >> 6;
    const int lane = tid & 63;
    const int lm = lane & 31, g = lane >> 5;
    const int bh  = blockIdx.z * H_ + blockIdx.y;
    const int qrow = blockIdx.x * 128 + wid*32 + lm;

    // Q fragments: slot (g,i), chunk c -> e = g*8 + i + 16c  (contiguous 16B)
    bf16x8 qf[4];
    const ushort* qptr = Q + (((size_t)bh)*N_ + qrow)*64 + g*8;
#pragma unroll
    for (int c = 0; c < 4; c++)
        qf[c] = *(const bf16x8*)(qptr + c*16);

    f32x16 acc0 = {0.f}, acc1 = {0.f};
    float den = 0.f;

    const ushort* kg = K  + ((size_t)bh)*N_*64;
    const ushort* vg = Vt + ((size_t)bh)*64*N_;
    char* kl = (char*)Klds;
    char* vl = (char*)Vlds;
    const int strow = tid >> 2;        // 0..63
    const int stcol = tid & 3;         // 0..3

    for (int kt = 0; kt < N_; kt += KT_) {
        __syncthreads();
#pragma unroll
        for (int q2 = 0; q2 < 2; q2++) {
            int cb = stcol*32 + q2*16;                       // byte col 0..127
            int4 kv = *(const int4*)((const char*)(kg + (size_t)(kt + strow)*64) + cb);
            *(int4*)(kl + strow*128 + (cb ^ ((strow & 7) << 4))) = kv;
            int4 vv = *(const int4*)((const char*)(vg + (size_t)strow*N_ + kt) + cb);
            int sw = (strow & 7) << 3;
            *(uint2*)(vl + strow*128 + ( cb      ^ sw)) = make_uint2((uint)vv.x, (uint)vv.y);
            *(uint2*)(vl + strow*128 + ((cb + 8) ^ sw)) = make_uint2((uint)vv.z, (uint)vv.w);
        }
        __syncthreads();

#pragma unroll
        for (int sub = 0; sub < 2; sub++) {
            // ---- S^T tile: 32 keys x 32 queries ----
            f32x16 st = {0.f};
            const int krow = sub*32 + lm;
            const int ksw  = (krow & 7) << 4;
#pragma unroll
            for (int c = 0; c < 4; c++) {
                bf16x8 kf = *(const bf16x8*)(kl + krow*128 + ((g*16 + c*32) ^ ksw));
                st = __builtin_amdgcn_mfma_f32_32x32x16_bf16(kf, qf[c], st, 0, 0, 0);
            }
            // ---- exp + den + pack P^T fragments ----
            float p[16];
#pragma unroll
            for (int r = 0; r < 16; r++) {
                p[r] = __expf(st[r]);      // score <= -0.125: never overflows
                den += p[r];
            }
            bf16x8 pf[2];
#pragma unroll
            for (int c = 0; c < 2; c++)
#pragma unroll
                for (int i = 0; i < 8; i++)
                    pf[c][i] = (short)f2bf(p[8*c + i]);
            // ---- PV: out^T += V^T * P^T ----
#pragma unroll
            for (int c = 0; c < 2; c++) {
#pragma unroll
                for (int dh = 0; dh < 2; dh++) {
                    const int vrow = dh*32 + lm;
                    const int vsw  = (vrow & 7) << 3;
                    const int colb = sub*64 + 8*g + 32*c;
                    union { uint2 u2[2]; bf16x8 v; } uu;
                    uu.u2[0] = *(const uint2*)(vl + vrow*128 + ( colb       ^ vsw));
                    uu.u2[1] = *(const uint2*)(vl + vrow*128 + ((colb + 16) ^ vsw));
                    if (dh == 0)
                        acc0 = __builtin_amdgcn_mfma_f32_32x32x16_bf16(uu.v, pf[c], acc0, 0, 0, 0);
                    else
                        acc1 = __builtin_amdgcn_mfma_f32_32x32x16_bf16(uu.v, pf[c], acc1, 0, 0, 0);
                }
            }
        }
    }

    // ---- epilogue: normalize, expmap0 ----
    den += __shfl_xor(den, 32);
    float invd = 1.f / den;
    float ss = 0.f;
#pragma unroll
    for (int r = 0; r < 16; r++) {
        acc0[r] *= invd; acc1[r] *= invd;
        ss += acc0[r]*acc0[r] + acc1[r]*acc1[r];
    }
    ss += __shfl_xor(ss, 32);
    float rr = sqrtf(fmaxf(ss, 1e-14f));   // EPS^2
    float t  = coshf(rr);
    float coef = sconst * sinhf(rr) / rr;

    const int b = bh >> 3, h = bh & 7;
    const size_t ob = ((size_t)b*N_ + qrow)*505 + (size_t)h*DS_;  // + d gives out slot for dim d (d>=1)
#pragma unroll
    for (int r = 0; r < 16; r++) {
        int d = (r & 3) + 8*(r >> 2) + 4*g;
        if (d >= 1) out[ob + d] = coef * acc0[r];
        out[ob + d + 32] = coef * acc1[r];
    }
    if (g == 0) TS[((size_t)bh)*N_ + qrow] = t;
}

// ---------------- Kernel 3: cross-head t' --------------------------------
__global__ void tprime_kernel(const float* __restrict__ TS, float* __restrict__ out,
                              float sconst)
{
    int idx = blockIdx.x*256 + threadIdx.x;   // b*N + n
    if (idx >= B_*N_) return;
    int b = idx >> 10, n = idx & (N_ - 1);
    float sum = 0.f;
#pragma unroll
    for (int h = 0; h < H_; h++) {
        float t = TS[((size_t)(b*H_ + h))*N_ + n];
        sum += t*t - 1.f;    // invK = -1
    }
    float tp = sqrtf(fmaxf(sconst*sconst*sum + 1.f, 1e-8f));
    out[(size_t)idx*505] = tp;
}

static double digamma_(double x) {
    double r = 0.0;
    while (x < 20.0) { r -= 1.0/x; x += 1.0; }
    double f = 1.0/(x*x);
    return r + log(x) - 0.5/x - f*(1.0/12.0 - f*(1.0/120.0 - f*(1.0/252.0)));
}

extern "C" void kernel_launch(void* const* d_in, const int* in_sizes, int n_in,
                              void* d_out, int out_size, void* d_ws, size_t ws_size,
                              hipStream_t stream) {
    const float* x  = (const float*)d_in[0];
    const float* Wq = (const float*)d_in[1];
    const float* bq = (const float*)d_in[2];
    const float* Wk = (const float*)d_in[3];
    const float* bk = (const float*)d_in[4];
    const float* Wv = (const float*)d_in[5];
    const float* bv = (const float*)d_in[6];
    float* out = (float*)d_out;

    // ws: Q | K [B][H][N][64] bf16, Vt [B][H][64][N] bf16, TS [B][H][N] f32
    const size_t QKV = (size_t)B_*H_*N_*64;       // 4M elements
    ushort* Qd  = (ushort*)d_ws;
    ushort* Kd  = Qd + QKV;
    ushort* Vtd = Kd + QKV;
    float*  TS  = (float*)(Vtd + QKV);

    const float sconst = (float)exp(0.5*(digamma_(H_*DS_/2.0) - digamma_(DS_/2.0)));

    dim3 g1(128, H_, 3);
    proj_kernel<<<g1, 256, 0, stream>>>(x, Wq, bq, Wk, bk, Wv, bv, Qd, Kd, Vtd);
    dim3 g2(N_/128, H_, B_);
    attn_kernel<<<g2, 256, 0, stream>>>(Qd, Kd, Vtd, out, TS, sconst);
    tprime_kernel<<<(B_*N_ + 255)/256, 256, 0, stream>>>(TS, out, sconst);
}

// Round 3
// 87.995 us; speedup vs baseline: 11.8967x; 3.4518x over previous
//
#include <hip/hip_runtime.h>
#include <math.h>

#define B_ 8
#define N_ 1024
#define D_ 512
#define H_ 8
#define HD_ 64
#define DS_ 63
#define SCALE_ 0.125f
#define EPS_ 1e-7f
#define KT_ 64

typedef short bf16x8 __attribute__((ext_vector_type(8)));   // 8 bf16 in 4 VGPRs
typedef float f32x16 __attribute__((ext_vector_type(16)));

typedef const __attribute__((address_space(1))) unsigned int* gas_ptr;
typedef __attribute__((address_space(3))) unsigned int* las_ptr;

__device__ inline ushort f2bf(float f) {
    uint u = __float_as_uint(f);
    uint r = (u + 0x7FFFu + ((u >> 16) & 1u)) >> 16;
    return (ushort)r;
}

// ---------------- Kernel 0a: x fp32 -> bf16 --------------------------------
__global__ void xcast_kernel(const float* __restrict__ x, ushort* __restrict__ xb) {
    int i = blockIdx.x * 256 + threadIdx.x;          // one float4 each
    float4 v = ((const float4*)x)[i];
    ushort4 o;
    o.x = f2bf(v.x); o.y = f2bf(v.y); o.z = f2bf(v.z); o.w = f2bf(v.w);
    ((ushort4*)xb)[i] = o;
}

// ---------------- Kernel 0b: W -> Wt[group][e(64)][k(512)] bf16 ------------
// grid (24 groups, 8 k-chunks), block 256. group = mat*8+h. e==63 -> 0 pad.
__global__ void wprep_kernel(const float* __restrict__ Wq, const float* __restrict__ Wk,
                             const float* __restrict__ Wv, ushort* __restrict__ Wt) {
    __shared__ float til[64 * 65];
    const int g = blockIdx.x, kbase = blockIdx.y * 64;
    const int mat = g >> 3, h = g & 7;
    const float* W = (mat == 0) ? Wq : (mat == 1) ? Wk : Wv;
    const float* src = W + (size_t)h * D_ * DS_ + (size_t)kbase * DS_;
    for (int i = threadIdx.x; i < 64 * DS_; i += 256) {
        int k = i / DS_, e = i - k * DS_;
        til[k * 65 + e] = src[i];
    }
    __syncthreads();
    for (int i = threadIdx.x; i < 64 * 64; i += 256) {
        int e = i >> 6, kk = i & 63;
        float v = (e < DS_) ? til[kk * 65 + e] : 0.f;
        Wt[((size_t)g * 64 + e) * D_ + kbase + kk] = f2bf(v);
    }
}

// ---------------- Kernel 1: MFMA projection GEMM + lorentz epilogue --------
// grid (64 row-tiles, 24 groups), block 256 = 4 waves.
// C tile 128 rows x 64 cols(e). A = Xbf[8192][512], B = Wt[g][64][512] (stored col-major: [e][k]).
__global__ __launch_bounds__(256, 2)
void proj2_kernel(const ushort* __restrict__ Xb, const ushort* __restrict__ Wt,
                  const float* __restrict__ bq, const float* __restrict__ bk,
                  const float* __restrict__ bv,
                  ushort* __restrict__ Qo, ushort* __restrict__ Ko,
                  ushort* __restrict__ Vto)
{
    __shared__ char smem[49152];            // As[2][16K] + Bs[2][8K] | zs[128][65] f32
    __shared__ float tval[128], cval[128];

    const int tid = threadIdx.x;
    const int wid = tid >> 6, lane = tid & 63;
    const int lm = lane & 31, g = lane >> 5;
    const int R0 = blockIdx.x * 128;
    const int grp = blockIdx.y;
    const int mat = grp >> 3, h = grp & 7;

    char* As = smem;                         // [2][128 rows][128 B]
    char* Bs = smem + 32768;                 // [2][64 rows][128 B]
    const ushort* Wg = Wt + (size_t)grp * 64 * D_;

    f32x16 acc0 = {0.f}, acc1 = {0.f};

    // ---- staging helpers (linear LDS dest, inverse-swizzled global src) ----
    auto stageA = [&](int buf, int ktE) {
#pragma unroll
        for (int it = 0; it < 4; it++) {
            int ci = it * 256 + tid;                 // 16B chunk id, 1024 total
            int row = ci >> 3, cb = (ci & 7) * 16;
            const char* src = (const char*)(Xb + (size_t)(R0 + row) * D_ + ktE)
                              + (cb ^ ((row & 7) << 4));
            __builtin_amdgcn_global_load_lds((gas_ptr)src,
                (las_ptr)(As + buf * 16384 + it * 4096 + wid * 1024), 16, 0, 0);
        }
    };
    auto stageB = [&](int buf, int ktE) {
#pragma unroll
        for (int it = 0; it < 2; it++) {
            int ci = it * 256 + tid;                 // 512 chunks
            int row = ci >> 3, cb = (ci & 7) * 16;
            const char* src = (const char*)(Wg + (size_t)row * D_ + ktE)
                              + (cb ^ ((row & 7) << 4));
            __builtin_amdgcn_global_load_lds((gas_ptr)src,
                (las_ptr)(Bs + buf * 8192 + it * 4096 + wid * 1024), 16, 0, 0);
        }
    };

    stageA(0, 0); stageB(0, 0);
    __syncthreads();

    const int arow = wid * 32 + lm;
    const int asw = (lm & 7) << 4;

    for (int t = 0; t < 8; t++) {
        int cur = t & 1;
        if (t < 7) { stageA(cur ^ 1, (t + 1) * KT_); stageB(cur ^ 1, (t + 1) * KT_); }
        char* Ab = As + cur * 16384;
        char* Bb = Bs + cur * 8192;
#pragma unroll
        for (int c = 0; c < 4; c++) {
            int kb = (c * 32 + g * 16);
            bf16x8 af  = *(const bf16x8*)(Ab + arow * 128 + (kb ^ asw));
            bf16x8 bf0 = *(const bf16x8*)(Bb + lm * 128 + (kb ^ asw));
            bf16x8 bf1 = *(const bf16x8*)(Bb + (32 + lm) * 128 + (kb ^ asw));
            acc0 = __builtin_amdgcn_mfma_f32_32x32x16_bf16(af, bf0, acc0, 0, 0, 0);
            acc1 = __builtin_amdgcn_mfma_f32_32x32x16_bf16(af, bf1, acc1, 0, 0, 0);
        }
        if (t < 7) __syncthreads();
    }
    __syncthreads();   // LDS reuse for epilogue

    // ---- epilogue: bias, write z to LDS ----
    const float* bptr = (mat == 0) ? bq : (mat == 1) ? bk : bv;
    float bv0 = (lm < DS_) ? bptr[h * DS_ + lm] : 0.f;
    float bv1 = (lm + 32 < DS_) ? bptr[h * DS_ + lm + 32] : 0.f;
    float* zs = (float*)smem;                 // [128][65]
#pragma unroll
    for (int r = 0; r < 16; r++) {
        int row = wid * 32 + (r & 3) + 8 * (r >> 2) + 4 * g;
        zs[row * 65 + lm]      = acc0[r] + bv0;
        zs[row * 65 + 32 + lm] = acc1[r] + bv1;
    }
    __syncthreads();

    if (tid < 128) {
        float ss = 0.f;
        for (int e = 0; e < DS_; e++) { float v = zs[tid * 65 + e]; ss += v * v; }
        float t = sqrtf(ss + 1.f);
        float w0, coef;
        if (mat == 0)      { w0 = -t * SCALE_; coef = SCALE_; }
        else if (mat == 1) { w0 =  t;          coef = 1.f; }
        else {
            float tc = fmaxf(t, 1.f + EPS_);
            float d  = acoshf(tc);
            float dn = sqrtf(fmaxf(t * t - 1.f, EPS_));
            w0 = 0.f; coef = d / dn;
        }
        tval[tid] = w0; cval[tid] = coef;
    }
    __syncthreads();

    const int b = R0 >> 10, n0 = R0 & (N_ - 1);
    const int bh = b * H_ + h;
    if (mat == 2) {
        for (int i = tid; i < 128 * 64; i += 256) {
            int e = i >> 7, nl = i & 127;
            float val = (e == 0) ? 0.f : cval[nl] * zs[nl * 65 + e - 1];
            Vto[((size_t)bh * 64 + e) * N_ + n0 + nl] = f2bf(val);
        }
    } else {
        ushort* dst = (mat == 0) ? Qo : Ko;
        for (int i = tid; i < 128 * 64; i += 256) {
            int rr = i >> 6, e = i & 63;
            float val = (e == 0) ? tval[rr] : cval[rr] * zs[rr * 65 + e - 1];
            dst[((size_t)bh * N_ + n0 + rr) * 64 + e] = f2bf(val);
        }
    }
}

// ---------------- Kernel 2: MFMA attention + expmap0 (unchanged) -----------
__global__ __launch_bounds__(256, 2)
void attn_kernel(const ushort* __restrict__ Q, const ushort* __restrict__ K,
                 const ushort* __restrict__ Vt, float* __restrict__ out,
                 float* __restrict__ TS, float sconst)
{
    __shared__ ushort Klds[KT_*64];   // [key n][e], rows 128B, XOR (n&7)<<4
    __shared__ ushort Vlds[64*KT_];   // [d][n],    rows 128B, XOR (d&7)<<3

    const int tid  = threadIdx.x;
    const int wid  = tid >> 6;
    const int lane = tid & 63;
    const int lm = lane & 31, g = lane >> 5;
    const int bh  = blockIdx.z * H_ + blockIdx.y;
    const int qrow = blockIdx.x * 128 + wid*32 + lm;

    bf16x8 qf[4];
    const ushort* qptr = Q + (((size_t)bh)*N_ + qrow)*64 + g*8;
#pragma unroll
    for (int c = 0; c < 4; c++)
        qf[c] = *(const bf16x8*)(qptr + c*16);

    f32x16 acc0 = {0.f}, acc1 = {0.f};
    float den = 0.f;

    const ushort* kg = K  + ((size_t)bh)*N_*64;
    const ushort* vg = Vt + ((size_t)bh)*64*N_;
    char* kl = (char*)Klds;
    char* vl = (char*)Vlds;
    const int strow = tid >> 2;
    const int stcol = tid & 3;

    for (int kt = 0; kt < N_; kt += KT_) {
        __syncthreads();
#pragma unroll
        for (int q2 = 0; q2 < 2; q2++) {
            int cb = stcol*32 + q2*16;
            int4 kv = *(const int4*)((const char*)(kg + (size_t)(kt + strow)*64) + cb);
            *(int4*)(kl + strow*128 + (cb ^ ((strow & 7) << 4))) = kv;
            int4 vv = *(const int4*)((const char*)(vg + (size_t)strow*N_ + kt) + cb);
            int sw = (strow & 7) << 3;
            *(uint2*)(vl + strow*128 + ( cb      ^ sw)) = make_uint2((uint)vv.x, (uint)vv.y);
            *(uint2*)(vl + strow*128 + ((cb + 8) ^ sw)) = make_uint2((uint)vv.z, (uint)vv.w);
        }
        __syncthreads();

#pragma unroll
        for (int sub = 0; sub < 2; sub++) {
            f32x16 st = {0.f};
            const int krow = sub*32 + lm;
            const int ksw  = (krow & 7) << 4;
#pragma unroll
            for (int c = 0; c < 4; c++) {
                bf16x8 kf = *(const bf16x8*)(kl + krow*128 + ((g*16 + c*32) ^ ksw));
                st = __builtin_amdgcn_mfma_f32_32x32x16_bf16(kf, qf[c], st, 0, 0, 0);
            }
            float p[16];
#pragma unroll
            for (int r = 0; r < 16; r++) {
                p[r] = __expf(st[r]);      // score <= -0.125: never overflows
                den += p[r];
            }
            bf16x8 pf[2];
#pragma unroll
            for (int c = 0; c < 2; c++)
#pragma unroll
                for (int i = 0; i < 8; i++)
                    pf[c][i] = (short)f2bf(p[8*c + i]);
#pragma unroll
            for (int c = 0; c < 2; c++) {
#pragma unroll
                for (int dh = 0; dh < 2; dh++) {
                    const int vrow = dh*32 + lm;
                    const int vsw  = (vrow & 7) << 3;
                    const int colb = sub*64 + 8*g + 32*c;
                    union { uint2 u2[2]; bf16x8 v; } uu;
                    uu.u2[0] = *(const uint2*)(vl + vrow*128 + ( colb       ^ vsw));
                    uu.u2[1] = *(const uint2*)(vl + vrow*128 + ((colb + 16) ^ vsw));
                    if (dh == 0)
                        acc0 = __builtin_amdgcn_mfma_f32_32x32x16_bf16(uu.v, pf[c], acc0, 0, 0, 0);
                    else
                        acc1 = __builtin_amdgcn_mfma_f32_32x32x16_bf16(uu.v, pf[c], acc1, 0, 0, 0);
                }
            }
        }
    }

    den += __shfl_xor(den, 32);
    float invd = 1.f / den;
    float ss = 0.f;
#pragma unroll
    for (int r = 0; r < 16; r++) {
        acc0[r] *= invd; acc1[r] *= invd;
        ss += acc0[r]*acc0[r] + acc1[r]*acc1[r];
    }
    ss += __shfl_xor(ss, 32);
    float rr = sqrtf(fmaxf(ss, 1e-14f));
    float t  = coshf(rr);
    float coef = sconst * sinhf(rr) / rr;

    const int b = bh >> 3, h = bh & 7;
    const size_t ob = ((size_t)b*N_ + qrow)*505 + (size_t)h*DS_;
#pragma unroll
    for (int r = 0; r < 16; r++) {
        int d = (r & 3) + 8*(r >> 2) + 4*g;
        if (d >= 1) out[ob + d] = coef * acc0[r];
        out[ob + d + 32] = coef * acc1[r];
    }
    if (g == 0) TS[((size_t)bh)*N_ + qrow] = t;
}

// ---------------- Kernel 3: cross-head t' --------------------------------
__global__ void tprime_kernel(const float* __restrict__ TS, float* __restrict__ out,
                              float sconst)
{
    int idx = blockIdx.x*256 + threadIdx.x;
    if (idx >= B_*N_) return;
    int b = idx >> 10, n = idx & (N_ - 1);
    float sum = 0.f;
#pragma unroll
    for (int h = 0; h < H_; h++) {
        float t = TS[((size_t)(b*H_ + h))*N_ + n];
        sum += t*t - 1.f;
    }
    float tp = sqrtf(fmaxf(sconst*sconst*sum + 1.f, 1e-8f));
    out[(size_t)idx*505] = tp;
}

static double digamma_(double x) {
    double r = 0.0;
    while (x < 20.0) { r -= 1.0/x; x += 1.0; }
    double f = 1.0/(x*x);
    return r + log(x) - 0.5/x - f*(1.0/12.0 - f*(1.0/120.0 - f*(1.0/252.0)));
}

extern "C" void kernel_launch(void* const* d_in, const int* in_sizes, int n_in,
                              void* d_out, int out_size, void* d_ws, size_t ws_size,
                              hipStream_t stream) {
    const float* x  = (const float*)d_in[0];
    const float* Wq = (const float*)d_in[1];
    const float* bq = (const float*)d_in[2];
    const float* Wk = (const float*)d_in[3];
    const float* bk = (const float*)d_in[4];
    const float* Wv = (const float*)d_in[5];
    const float* bv = (const float*)d_in[6];
    float* out = (float*)d_out;

    const size_t QKV = (size_t)B_*H_*N_*64;          // 4M elems
    ushort* Qd  = (ushort*)d_ws;
    ushort* Kd  = Qd + QKV;
    ushort* Vtd = Kd + QKV;
    ushort* Xb  = Vtd + QKV;                         // 4M elems
    ushort* Wtd = Xb + (size_t)B_*N_*D_;             // 24*64*512
    float*  TS  = (float*)(Wtd + (size_t)24*64*D_);

    const float sconst = (float)exp(0.5*(digamma_(H_*DS_/2.0) - digamma_(DS_/2.0)));

    xcast_kernel<<<(B_*N_*D_/4 + 255)/256, 256, 0, stream>>>(x, Xb);
    wprep_kernel<<<dim3(24, 8), 256, 0, stream>>>(Wq, Wk, Wv, Wtd);
    proj2_kernel<<<dim3(64, 24), 256, 0, stream>>>(Xb, Wtd, bq, bk, bv, Qd, Kd, Vtd);
    dim3 g2(N_/128, H_, B_);
    attn_kernel<<<g2, 256, 0, stream>>>(Qd, Kd, Vtd, out, TS, sconst);
    tprime_kernel<<<(B_*N_ + 255)/256, 256, 0, stream>>>(TS, out, sconst);
}

// Round 4
// 78.405 us; speedup vs baseline: 13.3518x; 1.1223x over previous
//
#include <hip/hip_runtime.h>
#include <math.h>

#define B_ 8
#define N_ 1024
#define D_ 512
#define H_ 8
#define HD_ 64
#define DS_ 63
#define SCALE_ 0.125f
#define EPS_ 1e-7f
#define KT_ 64

typedef short bf16x8 __attribute__((ext_vector_type(8)));   // 8 bf16 in 4 VGPRs
typedef float f32x16 __attribute__((ext_vector_type(16)));

typedef const __attribute__((address_space(1))) unsigned int* gas_ptr;
typedef __attribute__((address_space(3))) unsigned int* las_ptr;

__device__ inline ushort f2bf(float f) {
    uint u = __float_as_uint(f);
    uint r = (u + 0x7FFFu + ((u >> 16) & 1u)) >> 16;
    return (ushort)r;
}

// ---------------- Kernel 0a: x fp32 -> bf16 --------------------------------
__global__ void xcast_kernel(const float* __restrict__ x, ushort* __restrict__ xb) {
    int i = blockIdx.x * 256 + threadIdx.x;          // one float4 each
    float4 v = ((const float4*)x)[i];
    ushort4 o;
    o.x = f2bf(v.x); o.y = f2bf(v.y); o.z = f2bf(v.z); o.w = f2bf(v.w);
    ((ushort4*)xb)[i] = o;
}

// ---------------- Kernel 0b: W -> Wt[group][e(64)][k(512)] bf16 ------------
__global__ void wprep_kernel(const float* __restrict__ Wq, const float* __restrict__ Wk,
                             const float* __restrict__ Wv, ushort* __restrict__ Wt) {
    __shared__ float til[64 * 65];
    const int g = blockIdx.x, kbase = blockIdx.y * 64;
    const int mat = g >> 3, h = g & 7;
    const float* W = (mat == 0) ? Wq : (mat == 1) ? Wk : Wv;
    const float* src = W + (size_t)h * D_ * DS_ + (size_t)kbase * DS_;
    for (int i = threadIdx.x; i < 64 * DS_; i += 256) {
        int k = i / DS_, e = i - k * DS_;
        til[k * 65 + e] = src[i];
    }
    __syncthreads();
    for (int i = threadIdx.x; i < 64 * 64; i += 256) {
        int e = i >> 6, kk = i & 63;
        float v = (e < DS_) ? til[kk * 65 + e] : 0.f;
        Wt[((size_t)g * 64 + e) * D_ + kbase + kk] = f2bf(v);
    }
}

// ---------------- Kernel 1: MFMA projection GEMM + lorentz epilogue --------
__global__ __launch_bounds__(256, 2)
void proj2_kernel(const ushort* __restrict__ Xb, const ushort* __restrict__ Wt,
                  const float* __restrict__ bq, const float* __restrict__ bk,
                  const float* __restrict__ bv,
                  ushort* __restrict__ Qo, ushort* __restrict__ Ko,
                  ushort* __restrict__ Vto)
{
    __shared__ char smem[49152];
    __shared__ float tval[128], cval[128];

    const int tid = threadIdx.x;
    const int wid = tid >> 6, lane = tid & 63;
    const int lm = lane & 31, g = lane >> 5;
    const int R0 = blockIdx.x * 128;
    const int grp = blockIdx.y;
    const int mat = grp >> 3, h = grp & 7;

    char* As = smem;                         // [2][128 rows][128 B]
    char* Bs = smem + 32768;                 // [2][64 rows][128 B]
    const ushort* Wg = Wt + (size_t)grp * 64 * D_;

    f32x16 acc0 = {0.f}, acc1 = {0.f};

    auto stageA = [&](int buf, int ktE) {
#pragma unroll
        for (int it = 0; it < 4; it++) {
            int ci = it * 256 + tid;
            int row = ci >> 3, cb = (ci & 7) * 16;
            const char* src = (const char*)(Xb + (size_t)(R0 + row) * D_ + ktE)
                              + (cb ^ ((row & 7) << 4));
            __builtin_amdgcn_global_load_lds((gas_ptr)src,
                (las_ptr)(As + buf * 16384 + it * 4096 + wid * 1024), 16, 0, 0);
        }
    };
    auto stageB = [&](int buf, int ktE) {
#pragma unroll
        for (int it = 0; it < 2; it++) {
            int ci = it * 256 + tid;
            int row = ci >> 3, cb = (ci & 7) * 16;
            const char* src = (const char*)(Wg + (size_t)row * D_ + ktE)
                              + (cb ^ ((row & 7) << 4));
            __builtin_amdgcn_global_load_lds((gas_ptr)src,
                (las_ptr)(Bs + buf * 8192 + it * 4096 + wid * 1024), 16, 0, 0);
        }
    };

    stageA(0, 0); stageB(0, 0);
    __syncthreads();

    const int arow = wid * 32 + lm;
    const int asw = (lm & 7) << 4;

    for (int t = 0; t < 8; t++) {
        int cur = t & 1;
        if (t < 7) { stageA(cur ^ 1, (t + 1) * KT_); stageB(cur ^ 1, (t + 1) * KT_); }
        char* Ab = As + cur * 16384;
        char* Bb = Bs + cur * 8192;
#pragma unroll
        for (int c = 0; c < 4; c++) {
            int kb = (c * 32 + g * 16);
            bf16x8 af  = *(const bf16x8*)(Ab + arow * 128 + (kb ^ asw));
            bf16x8 bf0 = *(const bf16x8*)(Bb + lm * 128 + (kb ^ asw));
            bf16x8 bf1 = *(const bf16x8*)(Bb + (32 + lm) * 128 + (kb ^ asw));
            acc0 = __builtin_amdgcn_mfma_f32_32x32x16_bf16(af, bf0, acc0, 0, 0, 0);
            acc1 = __builtin_amdgcn_mfma_f32_32x32x16_bf16(af, bf1, acc1, 0, 0, 0);
        }
        if (t < 7) __syncthreads();
    }
    __syncthreads();

    const float* bptr = (mat == 0) ? bq : (mat == 1) ? bk : bv;
    float bv0 = (lm < DS_) ? bptr[h * DS_ + lm] : 0.f;
    float bv1 = (lm + 32 < DS_) ? bptr[h * DS_ + lm + 32] : 0.f;
    float* zs = (float*)smem;                 // [128][65]
#pragma unroll
    for (int r = 0; r < 16; r++) {
        int row = wid * 32 + (r & 3) + 8 * (r >> 2) + 4 * g;
        zs[row * 65 + lm]      = acc0[r] + bv0;
        zs[row * 65 + 32 + lm] = acc1[r] + bv1;
    }
    __syncthreads();

    if (tid < 128) {
        float ss = 0.f;
        for (int e = 0; e < DS_; e++) { float v = zs[tid * 65 + e]; ss += v * v; }
        float t = sqrtf(ss + 1.f);
        float w0, coef;
        if (mat == 0)      { w0 = -t * SCALE_; coef = SCALE_; }
        else if (mat == 1) { w0 =  t;          coef = 1.f; }
        else {
            float tc = fmaxf(t, 1.f + EPS_);
            float d  = acoshf(tc);
            float dn = sqrtf(fmaxf(t * t - 1.f, EPS_));
            w0 = 0.f; coef = d / dn;
        }
        tval[tid] = w0; cval[tid] = coef;
    }
    __syncthreads();

    const int b = R0 >> 10, n0 = R0 & (N_ - 1);
    const int bh = b * H_ + h;
    if (mat == 2) {
        for (int i = tid; i < 128 * 64; i += 256) {
            int e = i >> 7, nl = i & 127;
            float val = (e == 0) ? 0.f : cval[nl] * zs[nl * 65 + e - 1];
            Vto[((size_t)bh * 64 + e) * N_ + n0 + nl] = f2bf(val);
        }
    } else {
        ushort* dst = (mat == 0) ? Qo : Ko;
        for (int i = tid; i < 128 * 64; i += 256) {
            int rr = i >> 6, e = i & 63;
            float val = (e == 0) ? tval[rr] : cval[rr] * zs[rr * 65 + e - 1];
            dst[((size_t)bh * N_ + n0 + rr) * 64 + e] = f2bf(val);
        }
    }
}

// ---------------- Kernel 2: MFMA attention, split-K + XCD-local ------------
// 1-D grid 1024 blocks, 256 thr = 4 waves: wave = (r = row-half, s = key-half).
// bh = (idx>>4)*8 + (bid&7) so all n-tiles of a head live on one XCD's L2.
// Staging via global_load_lds (linear dest, inverse-XOR source). Partial
// (acc,den) from s=1 waves combined through LDS, epilogue on s=0 waves.
__global__ __launch_bounds__(256, 4)
void attn2_kernel(const ushort* __restrict__ Q, const ushort* __restrict__ K,
                  const ushort* __restrict__ Vt, float* __restrict__ out,
                  float* __restrict__ TS, float sconst)
{
    __shared__ char lds[32768];   // K: [s][64][128B] @0, V: [s][64][128B] @16K

    const int tid  = threadIdx.x;
    const int lane = tid & 63;
    const int lm = lane & 31, g = lane >> 5;
    const int r = (tid >> 6) & 1, s = tid >> 7;
    const int ptid = tid & 127, pw = ptid >> 6;

    const int bid = blockIdx.x;
    const int idx = bid >> 3;
    const int bh  = (idx >> 4) * 8 + (bid & 7);
    const int R0  = (idx & 15) * 64;
    const int qrow = R0 + r * 32 + lm;

    bf16x8 qf[4];
    const ushort* qptr = Q + (((size_t)bh) * N_ + qrow) * 64 + g * 8;
#pragma unroll
    for (int c = 0; c < 4; c++)
        qf[c] = *(const bf16x8*)(qptr + c * 16);

    f32x16 acc0 = {0.f}, acc1 = {0.f};
    float den = 0.f;

    const ushort* kg = K  + ((size_t)bh) * N_ * 64;
    const ushort* vg = Vt + ((size_t)bh) * 64 * N_;
    char* kbase = lds + s * 8192;
    char* vbase = lds + 16384 + s * 8192;

    for (int t = 0; t < 8; t++) {
        __syncthreads();                       // prior compute done before overwrite
        const int ks = s * 512 + t * 64;       // this wave-pair's 64-key tile
#pragma unroll
        for (int it = 0; it < 4; it++) {
            int ci = it * 128 + ptid;          // 16B chunk id within 8KB half-tile
            int row = ci >> 3, cb = (ci & 7) << 4;
            int sw = (row & 7) << 4;
            const char* srck = (const char*)(kg + (size_t)(ks + row) * 64) + (cb ^ sw);
            __builtin_amdgcn_global_load_lds((gas_ptr)srck,
                (las_ptr)(kbase + it * 2048 + pw * 1024), 16, 0, 0);
            const char* srcv = (const char*)(vg + (size_t)row * N_ + ks) + (cb ^ sw);
            __builtin_amdgcn_global_load_lds((gas_ptr)srcv,
                (las_ptr)(vbase + it * 2048 + pw * 1024), 16, 0, 0);
        }
        __syncthreads();                       // vmcnt(0) drain + barrier

#pragma unroll
        for (int sub = 0; sub < 2; sub++) {
            // ---- S^T: 32 keys x 32 queries ----
            f32x16 st = {0.f};
            const int krow = sub * 32 + lm;
            const int ksw  = (krow & 7) << 4;
#pragma unroll
            for (int c = 0; c < 4; c++) {
                bf16x8 kf = *(const bf16x8*)(kbase + krow * 128 + ((g * 16 + c * 32) ^ ksw));
                st = __builtin_amdgcn_mfma_f32_32x32x16_bf16(kf, qf[c], st, 0, 0, 0);
            }
            // ---- exp + den + pack P^T ----
            float p[16];
#pragma unroll
            for (int rr = 0; rr < 16; rr++) {
                p[rr] = __expf(st[rr]);        // score <= -0.125: never overflows
                den += p[rr];
            }
            bf16x8 pf[2];
#pragma unroll
            for (int c = 0; c < 2; c++)
#pragma unroll
                for (int i = 0; i < 8; i++)
                    pf[c][i] = (short)f2bf(p[8 * c + i]);
            // ---- PV: out^T += V^T * P^T ----
#pragma unroll
            for (int c = 0; c < 2; c++) {
#pragma unroll
                for (int dh = 0; dh < 2; dh++) {
                    const int vrow = dh * 32 + lm;
                    const int vsw  = (vrow & 7) << 4;
                    const int colb = sub * 64 + 8 * g + 32 * c;
                    union { uint2 u2[2]; bf16x8 v; } uu;
                    uu.u2[0] = *(const uint2*)(vbase + vrow * 128 + ( colb       ^ vsw));
                    uu.u2[1] = *(const uint2*)(vbase + vrow * 128 + ((colb + 16) ^ vsw));
                    if (dh == 0)
                        acc0 = __builtin_amdgcn_mfma_f32_32x32x16_bf16(uu.v, pf[c], acc0, 0, 0, 0);
                    else
                        acc1 = __builtin_amdgcn_mfma_f32_32x32x16_bf16(uu.v, pf[c], acc1, 0, 0, 0);
                }
            }
        }
    }

    // ---- combine key-halves through LDS ----
    __syncthreads();
    float* fl = (float*)lds;
    const int ib = (((r * 2 + g) * 32) + lm) * 33;
    if (s == 1) {
#pragma unroll
        for (int j = 0; j < 16; j++) { fl[ib + j] = acc0[j]; fl[ib + 16 + j] = acc1[j]; }
        fl[ib + 32] = den;
    }
    __syncthreads();
    if (s == 0) {
#pragma unroll
        for (int j = 0; j < 16; j++) { acc0[j] += fl[ib + j]; acc1[j] += fl[ib + 16 + j]; }
        den += fl[ib + 32];

        den += __shfl_xor(den, 32);
        float invd = 1.f / den;
        float ss = 0.f;
#pragma unroll
        for (int j = 0; j < 16; j++) {
            acc0[j] *= invd; acc1[j] *= invd;
            ss += acc0[j] * acc0[j] + acc1[j] * acc1[j];
        }
        ss += __shfl_xor(ss, 32);
        float rr = sqrtf(fmaxf(ss, 1e-14f));
        float t  = coshf(rr);
        float coef = sconst * sinhf(rr) / rr;

        const int b = bh >> 3, h = bh & 7;
        const size_t ob = ((size_t)b * N_ + qrow) * 505 + (size_t)h * DS_;
#pragma unroll
        for (int j = 0; j < 16; j++) {
            int d = (j & 3) + 8 * (j >> 2) + 4 * g;
            if (d >= 1) out[ob + d] = coef * acc0[j];
            out[ob + d + 32] = coef * acc1[j];
        }
        if (g == 0) TS[((size_t)bh) * N_ + qrow] = t;
    }
}

// ---------------- Kernel 3: cross-head t' --------------------------------
__global__ void tprime_kernel(const float* __restrict__ TS, float* __restrict__ out,
                              float sconst)
{
    int idx = blockIdx.x * 256 + threadIdx.x;
    if (idx >= B_ * N_) return;
    int b = idx >> 10, n = idx & (N_ - 1);
    float sum = 0.f;
#pragma unroll
    for (int h = 0; h < H_; h++) {
        float t = TS[((size_t)(b * H_ + h)) * N_ + n];
        sum += t * t - 1.f;
    }
    float tp = sqrtf(fmaxf(sconst * sconst * sum + 1.f, 1e-8f));
    out[(size_t)idx * 505] = tp;
}

static double digamma_(double x) {
    double r = 0.0;
    while (x < 20.0) { r -= 1.0 / x; x += 1.0; }
    double f = 1.0 / (x * x);
    return r + log(x) - 0.5 / x - f * (1.0 / 12.0 - f * (1.0 / 120.0 - f * (1.0 / 252.0)));
}

extern "C" void kernel_launch(void* const* d_in, const int* in_sizes, int n_in,
                              void* d_out, int out_size, void* d_ws, size_t ws_size,
                              hipStream_t stream) {
    const float* x  = (const float*)d_in[0];
    const float* Wq = (const float*)d_in[1];
    const float* bq = (const float*)d_in[2];
    const float* Wk = (const float*)d_in[3];
    const float* bk = (const float*)d_in[4];
    const float* Wv = (const float*)d_in[5];
    const float* bv = (const float*)d_in[6];
    float* out = (float*)d_out;

    const size_t QKV = (size_t)B_ * H_ * N_ * 64;
    ushort* Qd  = (ushort*)d_ws;
    ushort* Kd  = Qd + QKV;
    ushort* Vtd = Kd + QKV;
    ushort* Xb  = Vtd + QKV;
    ushort* Wtd = Xb + (size_t)B_ * N_ * D_;
    float*  TS  = (float*)(Wtd + (size_t)24 * 64 * D_);

    const float sconst = (float)exp(0.5 * (digamma_(H_ * DS_ / 2.0) - digamma_(DS_ / 2.0)));

    xcast_kernel<<<(B_ * N_ * D_ / 4 + 255) / 256, 256, 0, stream>>>(x, Xb);
    wprep_kernel<<<dim3(24, 8), 256, 0, stream>>>(Wq, Wk, Wv, Wtd);
    proj2_kernel<<<dim3(64, 24), 256, 0, stream>>>(Xb, Wtd, bq, bk, bv, Qd, Kd, Vtd);
    attn2_kernel<<<1024, 256, 0, stream>>>(Qd, Kd, Vtd, out, TS, sconst);
    tprime_kernel<<<(B_ * N_ + 255) / 256, 256, 0, stream>>>(TS, out, sconst);
}